// Round 14
// baseline (327.552 us; speedup 1.0000x reference)
//
#include <hip/hip_runtime.h>
#include <math.h>

#define EPSF 1e-5f
typedef __attribute__((ext_vector_type(2))) float f32x2;
typedef __attribute__((ext_vector_type(4))) float f32x4;

__device__ __forceinline__ float sigf(float x) { return 1.f / (1.f + __expf(-x)); }
__device__ __forceinline__ float tanhf_fast(float x) { return 1.f - 2.f / (__expf(2.f * x) + 1.f); }
__device__ __forceinline__ float rdlane(float v, int k) {
    return __int_as_float(__builtin_amdgcn_readlane(__float_as_int(v), k));
}

__device__ __forceinline__ float pauliv(int p, int r, int c) {
    switch (p) {
        case 0: return (r == c) ? 1.f : 0.f;
        case 1: return (r != c) ? 1.f : 0.f;
        case 2: return (r == 0 && c == 1) ? 1.f : ((r == 1 && c == 0) ? -1.f : 0.f);
        default: return (r == c) ? ((r == 0) ? 1.f : -1.f) : 0.f;
    }
}

// ---------------------------------------------------------------------------
// Kernel 1: the two 64-input MLPs. block 0 = bd -> blk, block 1 = fd -> freq
// ---------------------------------------------------------------------------
__device__ void mlp64_body(const float* __restrict__ xin,
                           const float* __restrict__ Win,   // 64x128
                           const float* __restrict__ bin_,
                           const float* __restrict__ Wmid,  // 2x128x128
                           const float* __restrict__ bmid,
                           const float* __restrict__ Wout,  // 128x36
                           const float* __restrict__ bout,
                           const float* __restrict__ gamma,
                           const float* __restrict__ beta,
                           float* __restrict__ out)         // 32x36
{
    __shared__ float sX[2048];
    __shared__ float sA[4096];
    __shared__ float sB[4096];
    __shared__ float sMu[128], sRs[128];
    int tid = threadIdx.x;

    for (int idx = tid; idx < 2048; idx += 1024) {
        int b = idx >> 6, c = idx & 63;
        sX[idx] = xin[b * 128 + c];
    }
    __syncthreads();

    for (int idx = tid; idx < 4096; idx += 1024) {
        int b = idx >> 7, j = idx & 127;
        float acc = bin_[j];
        for (int c = 0; c < 64; ++c) acc = fmaf(sX[b * 64 + c], Win[c * 128 + j], acc);
        sA[idx] = fmaxf(acc, 0.f);
    }
    __syncthreads();

    float* cur = sA;
    float* nxt = sB;
    for (int l = 0; l < 3; ++l) {
        if (tid < 128) {
            float s = 0.f, s2 = 0.f;
            for (int b = 0; b < 32; ++b) {
                float v = cur[b * 128 + tid];
                s += v; s2 += v * v;
            }
            float mu = s * (1.f / 32.f);
            float var = s2 * (1.f / 32.f) - mu * mu;
            sMu[tid] = mu;
            sRs[tid] = rsqrtf(var + EPSF);
        }
        __syncthreads();
        for (int idx = tid; idx < 4096; idx += 1024) {
            int j = idx & 127;
            cur[idx] = gamma[l * 128 + j] * (cur[idx] - sMu[j]) * sRs[j] + beta[l * 128 + j];
        }
        __syncthreads();
        if (l < 2) {
            for (int idx = tid; idx < 4096; idx += 1024) {
                int b = idx >> 7, j = idx & 127;
                float acc = bmid[l * 128 + j];
                for (int c = 0; c < 128; ++c)
                    acc = fmaf(cur[b * 128 + c], Wmid[(l * 128 + c) * 128 + j], acc);
                nxt[idx] = fmaxf(acc, 0.f);
            }
            __syncthreads();
            float* t = cur; cur = nxt; nxt = t;
        } else {
            for (int idx = tid; idx < 1152; idx += 1024) {
                int b = idx / 36, j = idx - b * 36;
                float acc = bout[j];
                for (int c = 0; c < 128; ++c)
                    acc = fmaf(cur[b * 128 + c], Wout[c * 36 + j], acc);
                out[idx] = fmaxf(acc, 0.f);
            }
        }
    }
}

__global__ __launch_bounds__(1024) void k_mlp2(
    const float* __restrict__ x,
    const float* fdWin, const float* fdbin, const float* fdWmid, const float* fdbmid,
    const float* fdWout, const float* fdbout, const float* fdg, const float* fdbt,
    const float* bdWin, const float* bdbin, const float* bdWmid, const float* bdbmid,
    const float* bdWout, const float* bdbout, const float* bdg, const float* bdbt,
    float* freq, float* blk)
{
    if (blockIdx.x == 0)
        mlp64_body(x + 64, bdWin, bdbin, bdWmid, bdbmid, bdWout, bdbout, bdg, bdbt, blk);
    else
        mlp64_body(x, fdWin, fdbin, fdWmid, fdbmid, fdWout, fdbout, fdg, fdbt, freq);
}

// ---------------------------------------------------------------------------
// Kernel 2a: per-s MLP mids + all 3 BNs -> normalized activations actW[s]
// ---------------------------------------------------------------------------
__global__ __launch_bounds__(512) void k_sc1(
    const float* __restrict__ freq,  // [b][s]
    const float* __restrict__ Win,   // [s][128]
    const float* __restrict__ bin_,  // [s][128]
    const float* __restrict__ Wmid,  // [s][2][128][128]
    const float* __restrict__ bmid,  // [s][2][128]
    const float* __restrict__ gamma, // [s][3][128]
    const float* __restrict__ beta,  // [s][3][128]
    float* __restrict__ actW)        // [s][32][128]
{
    int s = blockIdx.x, tid = threadIdx.x;
    __shared__ float sA[4096];
    __shared__ float sB[4096];
    __shared__ float sMu[128], sRs[128];
    const float* Wm = Wmid + (size_t)s * 2 * 128 * 128;
    const float* gm = gamma + s * 3 * 128;
    const float* bt = beta + s * 3 * 128;

    for (int idx = tid; idx < 4096; idx += 512) {
        int b = idx >> 7, j = idx & 127;
        float acc = fmaf(freq[b * 36 + s], Win[s * 128 + j], bin_[s * 128 + j]);
        sA[idx] = fmaxf(acc, 0.f);
    }
    __syncthreads();

    float* cur = sA;
    float* nxt = sB;
    for (int l = 0; l < 3; ++l) {
        if (tid < 128) {
            float sm = 0.f, s2 = 0.f;
            for (int b = 0; b < 32; ++b) {
                float v = cur[b * 128 + tid];
                sm += v; s2 += v * v;
            }
            float mu = sm * (1.f / 32.f);
            float var = s2 * (1.f / 32.f) - mu * mu;
            sMu[tid] = mu;
            sRs[tid] = rsqrtf(var + EPSF);
        }
        __syncthreads();
        for (int idx = tid; idx < 4096; idx += 512) {
            int j = idx & 127;
            cur[idx] = gm[l * 128 + j] * (cur[idx] - sMu[j]) * sRs[j] + bt[l * 128 + j];
        }
        __syncthreads();
        if (l < 2) {
            int jj = tid & 127, bb = tid >> 7;
            float acc[8];
            #pragma unroll
            for (int k = 0; k < 8; ++k) acc[k] = bmid[(s * 2 + l) * 128 + jj];
            for (int c = 0; c < 128; ++c) {
                float w = Wm[(l * 128 + c) * 128 + jj];
                #pragma unroll
                for (int k = 0; k < 8; ++k)
                    acc[k] = fmaf(cur[(bb + 4 * k) * 128 + c], w, acc[k]);
            }
            __syncthreads();
            #pragma unroll
            for (int k = 0; k < 8; ++k) nxt[(bb + 4 * k) * 128 + jj] = fmaxf(acc[k], 0.f);
            __syncthreads();
            float* t = cur; cur = nxt; nxt = t;
        } else {
            for (int idx = tid; idx < 4096; idx += 512)
                actW[(size_t)s * 4096 + idx] = cur[idx];
        }
    }
}

// ---------------------------------------------------------------------------
// Kernel 2b: out-proj (128->256) + relu + cos -> fseq2[s][b][t]
// ---------------------------------------------------------------------------
__global__ __launch_bounds__(512) void k_sc2(
    const float* __restrict__ actW,  // [s][32][128]
    const float* __restrict__ Wout,  // [s][128][256]
    const float* __restrict__ bout,  // [s][256]
    float* __restrict__ fseq2)       // [s][b][t]
{
    int bidx = blockIdx.x;
    int s = bidx >> 2, q = bidx & 3;
    int tid = threadIdx.x;
    __shared__ float sAct[4096];
    for (int idx = tid; idx < 4096; idx += 512)
        sAct[idx] = actW[(size_t)s * 4096 + idx];
    __syncthreads();

    int nn = (tid & 63) + q * 64;
    int bb = tid >> 6;                      // 0..7
    const float* Wo = Wout + (size_t)s * 128 * 256;
    float acc[4];
    #pragma unroll
    for (int k = 0; k < 4; ++k) acc[k] = bout[s * 256 + nn];
    #pragma unroll 4
    for (int c = 0; c < 128; ++c) {
        float w = Wo[c * 256 + nn];
        #pragma unroll
        for (int k = 0; k < 4; ++k)
            acc[k] = fmaf(sAct[(bb + 8 * k) * 128 + c], w, acc[k]);
    }
    #pragma unroll
    for (int k = 0; k < 4; ++k) {
        float v = fmaxf(acc[k], 0.f);
        fseq2[((size_t)s * 32 + bb + 8 * k) * 256 + nn] = __cosf(v);
    }
}

// ---------------------------------------------------------------------------
// Kernel 3: Xg[b][t][u][g] = bih+bhh + sum_s fseq2[s][b][t] * Wih[g*36+u][s]
// ---------------------------------------------------------------------------
__global__ __launch_bounds__(512) void k_xg(
    const float* __restrict__ fseq2, const float* __restrict__ Wih,
    const float* __restrict__ bih, const float* __restrict__ bhh,
    float* __restrict__ Xg)
{
    int t = blockIdx.x, tid = threadIdx.x;
    __shared__ float sF[1152];       // [b][s]
    __shared__ float sWt[36 * 144];  // [s][j]
    for (int idx = tid; idx < 1152; idx += 512) {
        int s = idx >> 5, b = idx & 31;
        sF[b * 36 + s] = fseq2[(size_t)idx * 256 + t];
    }
    for (int idx = tid; idx < 5184; idx += 512) {
        int j = idx / 36, s = idx - j * 36;
        sWt[s * 144 + j] = Wih[idx];
    }
    __syncthreads();
    for (int idx = tid; idx < 4608; idx += 512) {
        int b = idx / 144, j = idx - b * 144;
        int g = j / 36, u = j - g * 36;
        float acc = bih[j] + bhh[j];
        #pragma unroll
        for (int s = 0; s < 36; ++s)
            acc = fmaf(sF[b * 36 + s], sWt[s * 144 + j], acc);
        Xg[(((size_t)b * 256 + t) * 36 + u) * 4 + g] = acc;
    }
}

// ---------------------------------------------------------------------------
// Kernel 4: LSTM + output-zeroing fused.
// Blocks 0..31: LSTM, 2 waves/sample, gates split. KEY CHANGE (r13->r14):
//   h is written to LDS hbuf per step (lgkm-counted) and bulk-copied to
//   global AFTER the loop. r4-r13 all had a per-step GLOBAL h-store in the
//   loop; stores count against vmcnt, so each step's s_waitcnt vmcnt(N)
//   for the Xg pipe load also waited on older store acks (~store round
//   trip/step = the invariant ~700ns floor across 5 implementations).
//   Loop now contains ZERO global stores.
// Blocks 32+: grid-stride zero of the 268 MB output.
// ---------------------------------------------------------------------------
#define PF 8
#define NZBLK 4032
__global__ __launch_bounds__(128) void k_lstm_zero(
    const float* __restrict__ Xg,    // [b][t][36][4]  (i,f,g,o interleaved)
    const float* __restrict__ blk,   // [b][36]
    const float* __restrict__ Whh,   // [144][36] = [g*36+u][k]
    float* __restrict__ hseq2,       // [b][t][36]
    float* __restrict__ out, long total4)
{
    __shared__ float hbuf[256 * 36];  // 36 KB
    __shared__ f32x2 sEx[2][2][40];   // [t&1][wid][u]

    if (blockIdx.x >= 32) {
        f32x4* o = (f32x4*)out;
        f32x4 z = f32x4{0.f, 0.f, 0.f, 0.f};
        long start = (long)(blockIdx.x - 32) * 128 + threadIdx.x;
        long stride = (long)NZBLK * 128;
        for (long i = start; i < total4; i += stride) o[i] = z;
        return;
    }

    int b = blockIdx.x;
    int wid = threadIdx.x >> 6;      // 0: (i,f)   1: (g,o)
    int lane = threadIdx.x & 63;
    int uu = lane < 36 ? lane : 35;
    bool active = lane < 36;

    f32x2 w2[36];
    {
        const float* wA = Whh + (size_t)(wid * 72 + uu) * 36;       // i or g
        const float* wB = Whh + (size_t)(wid * 72 + 36 + uu) * 36;  // f or o
        #pragma unroll
        for (int k = 0; k < 36; ++k) w2[k] = f32x2{wA[k], wB[k]};
    }

    float hv = blk[b * 36 + uu];
    float c = 0.f;
    const f32x2* xb2 = (const f32x2*)(Xg + (size_t)b * 256 * 144);

    f32x2 pipe[PF];
    #pragma unroll
    for (int i = 0; i < PF; ++i) pipe[i] = xb2[(i * 36 + uu) * 2 + wid];

    #pragma unroll 8
    for (int t = 0; t < 256; ++t) {
        f32x2 acc0 = pipe[t & (PF - 1)];
        if (t + PF < 256) pipe[t & (PF - 1)] = xb2[((t + PF) * 36 + uu) * 2 + wid];

        f32x2 acc1 = f32x2{0.f, 0.f}, acc2 = f32x2{0.f, 0.f}, acc3 = f32x2{0.f, 0.f};
        #pragma unroll
        for (int k = 0; k < 36; k += 4) {
            float h0 = rdlane(hv, k),     h1 = rdlane(hv, k + 1);
            float h2 = rdlane(hv, k + 2), h3 = rdlane(hv, k + 3);
            acc0 = __builtin_elementwise_fma(w2[k],     f32x2{h0, h0}, acc0);
            acc1 = __builtin_elementwise_fma(w2[k + 1], f32x2{h1, h1}, acc1);
            acc2 = __builtin_elementwise_fma(w2[k + 2], f32x2{h2, h2}, acc2);
            acc3 = __builtin_elementwise_fma(w2[k + 3], f32x2{h3, h3}, acc3);
        }
        f32x2 a = (acc0 + acc1) + (acc2 + acc3);

        f32x2 mypair;
        if (wid == 0) mypair = f32x2{sigf(a.x), sigf(a.y)};        // {sig i, sig f}
        else          mypair = f32x2{tanhf_fast(a.x), sigf(a.y)};  // {tanh g, sig o}
        if (active) sEx[t & 1][wid][uu] = mypair;
        __syncthreads();
        f32x2 other = sEx[t & 1][wid ^ 1][uu];
        f32x2 ivfv = (wid == 0) ? mypair : other;   // {sig i, sig f}
        f32x2 gvov = (wid == 0) ? other : mypair;   // {tanh g, sig o}
        c = fmaf(ivfv.y, c, ivfv.x * gvov.x);
        hv = gvov.y * tanhf_fast(c);
        if (wid == 0 && active) hbuf[t * 36 + uu] = hv;   // LDS only (lgkm)
    }

    __syncthreads();
    // bulk flush LDS -> global (coalesced f32x4, outside the recurrence)
    {
        f32x4* dst = (f32x4*)(hseq2 + (size_t)b * 256 * 36);
        const f32x4* src = (const f32x4*)hbuf;
        for (int i = threadIdx.x; i < 2304; i += 128) dst[i] = src[i];
    }
}

// ---------------------------------------------------------------------------
// Kernel 5: mixed[b][o][n]; consumes hseq2[b][t][36]; LDS padded to 37
// ---------------------------------------------------------------------------
__global__ __launch_bounds__(256) void k_mixed(
    const float* __restrict__ blk, const float* __restrict__ hseq2,
    const float* __restrict__ mixW, const float* __restrict__ mixb,
    float* __restrict__ mixed)
{
    int bq = blockIdx.x;
    int b = bq >> 2, oq = bq & 3;        // 9 o's per block
    int tid = threadIdx.x;
    __shared__ float sH[256 * 37];
    __shared__ float sW[9 * 36];
    __shared__ float sBase[9];
    for (int idx = tid; idx < 9216; idx += 256) {
        int t = idx / 36, u = idx - t * 36;
        sH[t * 37 + u] = hseq2[(size_t)b * 9216 + idx];
    }
    for (int idx = tid; idx < 9 * 36; idx += 256) {
        int o = idx / 36, u = idx - o * 36;
        sW[idx] = mixW[(oq * 9 + o) * 72 + 36 + u];
    }
    if (tid < 9) {
        int o = oq * 9 + tid;
        float acc = mixb[o];
        for (int c = 0; c < 36; ++c) acc = fmaf(mixW[o * 72 + c], blk[b * 36 + c], acc);
        sBase[tid] = acc;
    }
    __syncthreads();
    int n = tid;
    #pragma unroll
    for (int o = 0; o < 9; ++o) {
        float acc = sBase[o];
        #pragma unroll
        for (int u = 0; u < 36; ++u)
            acc = fmaf(sW[o * 36 + u], sH[n * 37 + u], acc);
        mixed[((size_t)b * 36 + oq * 9 + o) * 256 + n] = acc;
    }
}

// ---------------------------------------------------------------------------
// Kernel 6: sparse nonzero writes into the pre-zeroed output
// ---------------------------------------------------------------------------
__global__ __launch_bounds__(256) void k_sparse(
    const float* __restrict__ mixed, float* __restrict__ out)
{
    int bg = blockIdx.x;
    int g = bg & 1, b = bg >> 1;
    int n = threadIdx.x;
    const float* mb = mixed + (size_t)b * 36 * 256;
    float vSub = mb[(size_t)g * 256 + n];
    float vSup = mb[(size_t)(2 + g) * 256 + n];
    float ch[16];
    #pragma unroll
    for (int k = 0; k < 16; ++k) ch[k] = mb[(size_t)(4 + 16 * g + k) * 256 + n];
    float d[16];
    #pragma unroll
    for (int e = 0; e < 16; ++e) {
        int r = e >> 2, cc = e & 3;
        float acc = 0.f;
        #pragma unroll
        for (int k = 0; k < 16; ++k) {
            float kv = pauliv(k >> 2, r >> 1, cc >> 1) * pauliv(k & 3, r & 1, cc & 1);
            if (kv == 1.f) acc = acc + ch[k];
            else if (kv == -1.f) acc = acc - ch[k];
        }
        d[e] = acc;
    }

    float* base = out + (size_t)bg * 1024 * 1024;
    #pragma unroll
    for (int r = 0; r < 4; ++r)
        *(f32x4*)(base + (size_t)(4 * n + r) * 1024 + 4 * n) =
            f32x4{d[r * 4 + 0], d[r * 4 + 1], d[r * 4 + 2], d[r * 4 + 3]};
    if (n > 0) {
        #pragma unroll
        for (int r = 0; r < 4; ++r)
            base[(size_t)(4 * n + r) * 1024 + 4 * (n - 1) + r] = (r < 2) ? vSub : -vSub;
    }
    if (n < 255) {
        #pragma unroll
        for (int r = 0; r < 4; ++r)
            base[(size_t)(4 * n + r) * 1024 + 4 * (n + 1) + r] = (r < 2) ? vSup : -vSup;
    }
}

// ---------------------------------------------------------------------------
extern "C" void kernel_launch(void* const* d_in, const int* in_sizes, int n_in,
                              void* d_out, int out_size, void* d_ws, size_t ws_size,
                              hipStream_t stream) {
    const float* x      = (const float*)d_in[0];
    const float* fdWin  = (const float*)d_in[1];
    const float* fdbin  = (const float*)d_in[2];
    const float* fdWmid = (const float*)d_in[3];
    const float* fdbmid = (const float*)d_in[4];
    const float* fdWout = (const float*)d_in[5];
    const float* fdbout = (const float*)d_in[6];
    const float* fdg    = (const float*)d_in[7];
    const float* fdbt   = (const float*)d_in[8];
    const float* bdWin  = (const float*)d_in[9];
    const float* bdbin  = (const float*)d_in[10];
    const float* bdWmid = (const float*)d_in[11];
    const float* bdbmid = (const float*)d_in[12];
    const float* bdWout = (const float*)d_in[13];
    const float* bdbout = (const float*)d_in[14];
    const float* bdg    = (const float*)d_in[15];
    const float* bdbt   = (const float*)d_in[16];
    const float* scWin  = (const float*)d_in[17];
    const float* scbin  = (const float*)d_in[18];
    const float* scWmid = (const float*)d_in[19];
    const float* scbmid = (const float*)d_in[20];
    const float* scWout = (const float*)d_in[21];
    const float* scbout = (const float*)d_in[22];
    const float* scg    = (const float*)d_in[23];
    const float* scbt   = (const float*)d_in[24];
    const float* Wih    = (const float*)d_in[25];
    const float* Whh    = (const float*)d_in[26];
    const float* bih    = (const float*)d_in[27];
    const float* bhh    = (const float*)d_in[28];
    const float* mixW   = (const float*)d_in[29];
    const float* mixb   = (const float*)d_in[30];

    float* ws    = (float*)d_ws;
    float* freq  = ws;                 // 1152            [b][s]
    float* blk   = ws + 1152;          // 1152            [b][s]
    float* fseq2 = ws + 2304;          // 294912          [s][b][t]
    float* Xg    = ws + 297216;        // 1179648         [b][t][36][4]
    float* hseq2 = ws + 1476864;       // 294912          [b][t][36]
    float* mixed = ws + 1771776;       // 294912          [b][o][n]
    float* actW  = Xg;                 // aliases Xg (dead until k_xg)

    float* out = (float*)d_out;
    long total4 = (long)out_size / 4;  // 16,777,216 f32x4

    k_mlp2<<<2, 1024, 0, stream>>>(x,
        fdWin, fdbin, fdWmid, fdbmid, fdWout, fdbout, fdg, fdbt,
        bdWin, bdbin, bdWmid, bdbmid, bdWout, bdbout, bdg, bdbt,
        freq, blk);
    k_sc1<<<36, 512, 0, stream>>>(freq, scWin, scbin, scWmid, scbmid, scg, scbt, actW);
    k_sc2<<<144, 512, 0, stream>>>(actW, scWout, scbout, fseq2);
    k_xg<<<256, 512, 0, stream>>>(fseq2, Wih, bih, bhh, Xg);
    k_lstm_zero<<<32 + NZBLK, 128, 0, stream>>>(Xg, blk, Whh, hseq2, out, total4);
    k_mixed<<<128, 256, 0, stream>>>(blk, hseq2, mixW, mixb, mixed);
    k_sparse<<<64, 256, 0, stream>>>(mixed, out);
}

// Round 15
// 321.686 us; speedup vs baseline: 1.0182x; 1.0182x over previous
//
#include <hip/hip_runtime.h>
#include <math.h>

#define EPSF 1e-5f
typedef __attribute__((ext_vector_type(2))) float f32x2;
typedef __attribute__((ext_vector_type(4))) float f32x4;

__device__ __forceinline__ float sigf(float x) { return 1.f / (1.f + __expf(-x)); }
__device__ __forceinline__ float tanhf_fast(float x) { return 1.f - 2.f / (__expf(2.f * x) + 1.f); }
__device__ __forceinline__ float rdlane(float v, int k) {
    return __int_as_float(__builtin_amdgcn_readlane(__float_as_int(v), k));
}

__device__ __forceinline__ float pauliv(int p, int r, int c) {
    switch (p) {
        case 0: return (r == c) ? 1.f : 0.f;
        case 1: return (r != c) ? 1.f : 0.f;
        case 2: return (r == 0 && c == 1) ? 1.f : ((r == 1 && c == 0) ? -1.f : 0.f);
        default: return (r == c) ? ((r == 0) ? 1.f : -1.f) : 0.f;
    }
}

// ---------------------------------------------------------------------------
// Kernel 1: the two 64-input MLPs (blocks 0,1) + 268 MB output zeroing
// (blocks 2..2047) fused into one dispatch — zero hides under the MLP phase
// instead of costing a dedicated ~45us dispatch, and far from the LSTM.
// ---------------------------------------------------------------------------
__device__ void mlp64_body(const float* __restrict__ xin,
                           const float* __restrict__ Win,   // 64x128
                           const float* __restrict__ bin_,
                           const float* __restrict__ Wmid,  // 2x128x128
                           const float* __restrict__ bmid,
                           const float* __restrict__ Wout,  // 128x36
                           const float* __restrict__ bout,
                           const float* __restrict__ gamma,
                           const float* __restrict__ beta,
                           float* __restrict__ out)         // 32x36
{
    __shared__ float sX[2048];
    __shared__ float sA[4096];
    __shared__ float sB[4096];
    __shared__ float sMu[128], sRs[128];
    int tid = threadIdx.x;

    for (int idx = tid; idx < 2048; idx += 1024) {
        int b = idx >> 6, c = idx & 63;
        sX[idx] = xin[b * 128 + c];
    }
    __syncthreads();

    for (int idx = tid; idx < 4096; idx += 1024) {
        int b = idx >> 7, j = idx & 127;
        float acc = bin_[j];
        for (int c = 0; c < 64; ++c) acc = fmaf(sX[b * 64 + c], Win[c * 128 + j], acc);
        sA[idx] = fmaxf(acc, 0.f);
    }
    __syncthreads();

    float* cur = sA;
    float* nxt = sB;
    for (int l = 0; l < 3; ++l) {
        if (tid < 128) {
            float s = 0.f, s2 = 0.f;
            for (int b = 0; b < 32; ++b) {
                float v = cur[b * 128 + tid];
                s += v; s2 += v * v;
            }
            float mu = s * (1.f / 32.f);
            float var = s2 * (1.f / 32.f) - mu * mu;
            sMu[tid] = mu;
            sRs[tid] = rsqrtf(var + EPSF);
        }
        __syncthreads();
        for (int idx = tid; idx < 4096; idx += 1024) {
            int j = idx & 127;
            cur[idx] = gamma[l * 128 + j] * (cur[idx] - sMu[j]) * sRs[j] + beta[l * 128 + j];
        }
        __syncthreads();
        if (l < 2) {
            for (int idx = tid; idx < 4096; idx += 1024) {
                int b = idx >> 7, j = idx & 127;
                float acc = bmid[l * 128 + j];
                for (int c = 0; c < 128; ++c)
                    acc = fmaf(cur[b * 128 + c], Wmid[(l * 128 + c) * 128 + j], acc);
                nxt[idx] = fmaxf(acc, 0.f);
            }
            __syncthreads();
            float* t = cur; cur = nxt; nxt = t;
        } else {
            for (int idx = tid; idx < 1152; idx += 1024) {
                int b = idx / 36, j = idx - b * 36;
                float acc = bout[j];
                for (int c = 0; c < 128; ++c)
                    acc = fmaf(cur[b * 128 + c], Wout[c * 36 + j], acc);
                out[idx] = fmaxf(acc, 0.f);
            }
        }
    }
}

__global__ __launch_bounds__(1024) void k_mlp2_zero(
    const float* __restrict__ x,
    const float* fdWin, const float* fdbin, const float* fdWmid, const float* fdbmid,
    const float* fdWout, const float* fdbout, const float* fdg, const float* fdbt,
    const float* bdWin, const float* bdbin, const float* bdWmid, const float* bdbmid,
    const float* bdWout, const float* bdbout, const float* bdg, const float* bdbt,
    float* freq, float* blk, float* out, long total4)
{
    if (blockIdx.x >= 2) {
        f32x4* o = (f32x4*)out;
        f32x4 z = f32x4{0.f, 0.f, 0.f, 0.f};
        long start = (long)(blockIdx.x - 2) * 1024 + threadIdx.x;
        long stride = (long)2046 * 1024;
        for (long i = start; i < total4; i += stride) o[i] = z;
        return;
    }
    if (blockIdx.x == 0)
        mlp64_body(x + 64, bdWin, bdbin, bdWmid, bdbmid, bdWout, bdbout, bdg, bdbt, blk);
    else
        mlp64_body(x, fdWin, fdbin, fdWmid, fdbmid, fdWout, fdbout, fdg, fdbt, freq);
}

// ---------------------------------------------------------------------------
// Kernel 2a: per-s MLP mids + all 3 BNs -> normalized activations actW[s]
// ---------------------------------------------------------------------------
__global__ __launch_bounds__(512) void k_sc1(
    const float* __restrict__ freq,  // [b][s]
    const float* __restrict__ Win,   // [s][128]
    const float* __restrict__ bin_,  // [s][128]
    const float* __restrict__ Wmid,  // [s][2][128][128]
    const float* __restrict__ bmid,  // [s][2][128]
    const float* __restrict__ gamma, // [s][3][128]
    const float* __restrict__ beta,  // [s][3][128]
    float* __restrict__ actW)        // [s][32][128]
{
    int s = blockIdx.x, tid = threadIdx.x;
    __shared__ float sA[4096];
    __shared__ float sB[4096];
    __shared__ float sMu[128], sRs[128];
    const float* Wm = Wmid + (size_t)s * 2 * 128 * 128;
    const float* gm = gamma + s * 3 * 128;
    const float* bt = beta + s * 3 * 128;

    for (int idx = tid; idx < 4096; idx += 512) {
        int b = idx >> 7, j = idx & 127;
        float acc = fmaf(freq[b * 36 + s], Win[s * 128 + j], bin_[s * 128 + j]);
        sA[idx] = fmaxf(acc, 0.f);
    }
    __syncthreads();

    float* cur = sA;
    float* nxt = sB;
    for (int l = 0; l < 3; ++l) {
        if (tid < 128) {
            float sm = 0.f, s2 = 0.f;
            for (int b = 0; b < 32; ++b) {
                float v = cur[b * 128 + tid];
                sm += v; s2 += v * v;
            }
            float mu = sm * (1.f / 32.f);
            float var = s2 * (1.f / 32.f) - mu * mu;
            sMu[tid] = mu;
            sRs[tid] = rsqrtf(var + EPSF);
        }
        __syncthreads();
        for (int idx = tid; idx < 4096; idx += 512) {
            int j = idx & 127;
            cur[idx] = gm[l * 128 + j] * (cur[idx] - sMu[j]) * sRs[j] + bt[l * 128 + j];
        }
        __syncthreads();
        if (l < 2) {
            int jj = tid & 127, bb = tid >> 7;
            float acc[8];
            #pragma unroll
            for (int k = 0; k < 8; ++k) acc[k] = bmid[(s * 2 + l) * 128 + jj];
            for (int c = 0; c < 128; ++c) {
                float w = Wm[(l * 128 + c) * 128 + jj];
                #pragma unroll
                for (int k = 0; k < 8; ++k)
                    acc[k] = fmaf(cur[(bb + 4 * k) * 128 + c], w, acc[k]);
            }
            __syncthreads();
            #pragma unroll
            for (int k = 0; k < 8; ++k) nxt[(bb + 4 * k) * 128 + jj] = fmaxf(acc[k], 0.f);
            __syncthreads();
            float* t = cur; cur = nxt; nxt = t;
        } else {
            for (int idx = tid; idx < 4096; idx += 512)
                actW[(size_t)s * 4096 + idx] = cur[idx];
        }
    }
}

// ---------------------------------------------------------------------------
// Kernel 2b: out-proj (128->256) + relu + cos -> fseq2[s][b][t]
// ---------------------------------------------------------------------------
__global__ __launch_bounds__(512) void k_sc2(
    const float* __restrict__ actW,  // [s][32][128]
    const float* __restrict__ Wout,  // [s][128][256]
    const float* __restrict__ bout,  // [s][256]
    float* __restrict__ fseq2)       // [s][b][t]
{
    int bidx = blockIdx.x;
    int s = bidx >> 2, q = bidx & 3;
    int tid = threadIdx.x;
    __shared__ float sAct[4096];
    for (int idx = tid; idx < 4096; idx += 512)
        sAct[idx] = actW[(size_t)s * 4096 + idx];
    __syncthreads();

    int nn = (tid & 63) + q * 64;
    int bb = tid >> 6;                      // 0..7
    const float* Wo = Wout + (size_t)s * 128 * 256;
    float acc[4];
    #pragma unroll
    for (int k = 0; k < 4; ++k) acc[k] = bout[s * 256 + nn];
    #pragma unroll 4
    for (int c = 0; c < 128; ++c) {
        float w = Wo[c * 256 + nn];
        #pragma unroll
        for (int k = 0; k < 4; ++k)
            acc[k] = fmaf(sAct[(bb + 8 * k) * 128 + c], w, acc[k]);
    }
    #pragma unroll
    for (int k = 0; k < 4; ++k) {
        float v = fmaxf(acc[k], 0.f);
        fseq2[((size_t)s * 32 + bb + 8 * k) * 256 + nn] = __cosf(v);
    }
}

// ---------------------------------------------------------------------------
// Kernel 3: Xg[b][t][u][g]; also zeroes the heater flag (block 0 tid 0)
// ---------------------------------------------------------------------------
__global__ __launch_bounds__(512) void k_xg(
    const float* __restrict__ fseq2, const float* __restrict__ Wih,
    const float* __restrict__ bih, const float* __restrict__ bhh,
    float* __restrict__ Xg, int* __restrict__ flag)
{
    if (blockIdx.x == 0 && threadIdx.x == 0) *flag = 0;
    int t = blockIdx.x, tid = threadIdx.x;
    __shared__ float sF[1152];       // [b][s]
    __shared__ float sWt[36 * 144];  // [s][j]
    for (int idx = tid; idx < 1152; idx += 512) {
        int s = idx >> 5, b = idx & 31;
        sF[b * 36 + s] = fseq2[(size_t)idx * 256 + t];
    }
    for (int idx = tid; idx < 5184; idx += 512) {
        int j = idx / 36, s = idx - j * 36;
        sWt[s * 144 + j] = Wih[idx];
    }
    __syncthreads();
    for (int idx = tid; idx < 4608; idx += 512) {
        int b = idx / 144, j = idx - b * 144;
        int g = j / 36, u = j - g * 36;
        float acc = bih[j] + bhh[j];
        #pragma unroll
        for (int s = 0; s < 36; ++s)
            acc = fmaf(sF[b * 36 + s], sWt[s * 144 + j], acc);
        Xg[(((size_t)b * 256 + t) * 36 + u) * 4 + g] = acc;
    }
}

// ---------------------------------------------------------------------------
// Kernel 4: LSTM (r14 body, unchanged) + VALU HEATER blocks.
// CLOCK EXPERIMENT: 7 structurally different LSTM loops all measured
// ~700ns/step vs an 80-150ns issue+latency model — consistent only with a
// low SCLK (DPM sees a ~98%-idle chip). Blocks 32..254 spin dependent-free
// FMAs (~100% VALU on ~200 CUs) to force the core clock up, polling a
// device-scope flag; LSTM blocks atomicAdd the flag at completion so the
// heaters exit immediately after. Hard cap guarantees termination.
// ---------------------------------------------------------------------------
#define PF 8
__global__ __launch_bounds__(128) void k_lstm_heat(
    const float* __restrict__ Xg,    // [b][t][36][4]  (i,f,g,o interleaved)
    const float* __restrict__ blk,   // [b][36]
    const float* __restrict__ Whh,   // [144][36] = [g*36+u][k]
    float* __restrict__ hseq2,       // [b][t][36]
    int* __restrict__ flag)
{
    __shared__ float hbuf[256 * 36];  // 36 KB
    __shared__ f32x2 sEx[2][2][40];   // [t&1][wid][u]

    if (blockIdx.x >= 32) {
        float a0 = 1.0f + threadIdx.x, a1 = 1.1f, a2 = 1.2f, a3 = 1.3f;
        for (int it = 0; it < 2000; ++it) {
            #pragma unroll
            for (int j = 0; j < 128; ++j) {
                a0 = fmaf(a0, 0.9999f, 0.0001f);
                a1 = fmaf(a1, 0.9999f, 0.0002f);
                a2 = fmaf(a2, 0.9999f, 0.0003f);
                a3 = fmaf(a3, 0.9999f, 0.0004f);
            }
            if (__hip_atomic_load(flag, __ATOMIC_RELAXED, __HIP_MEMORY_SCOPE_AGENT) >= 32)
                break;
        }
        asm volatile("" :: "v"(a0), "v"(a1), "v"(a2), "v"(a3));
        return;
    }

    int b = blockIdx.x;
    int wid = threadIdx.x >> 6;      // 0: (i,f)   1: (g,o)
    int lane = threadIdx.x & 63;
    int uu = lane < 36 ? lane : 35;
    bool active = lane < 36;

    f32x2 w2[36];
    {
        const float* wA = Whh + (size_t)(wid * 72 + uu) * 36;       // i or g
        const float* wB = Whh + (size_t)(wid * 72 + 36 + uu) * 36;  // f or o
        #pragma unroll
        for (int k = 0; k < 36; ++k) w2[k] = f32x2{wA[k], wB[k]};
    }

    float hv = blk[b * 36 + uu];
    float c = 0.f;
    const f32x2* xb2 = (const f32x2*)(Xg + (size_t)b * 256 * 144);

    f32x2 pipe[PF];
    #pragma unroll
    for (int i = 0; i < PF; ++i) pipe[i] = xb2[(i * 36 + uu) * 2 + wid];

    #pragma unroll 8
    for (int t = 0; t < 256; ++t) {
        f32x2 acc0 = pipe[t & (PF - 1)];
        if (t + PF < 256) pipe[t & (PF - 1)] = xb2[((t + PF) * 36 + uu) * 2 + wid];

        f32x2 acc1 = f32x2{0.f, 0.f}, acc2 = f32x2{0.f, 0.f}, acc3 = f32x2{0.f, 0.f};
        #pragma unroll
        for (int k = 0; k < 36; k += 4) {
            float h0 = rdlane(hv, k),     h1 = rdlane(hv, k + 1);
            float h2 = rdlane(hv, k + 2), h3 = rdlane(hv, k + 3);
            acc0 = __builtin_elementwise_fma(w2[k],     f32x2{h0, h0}, acc0);
            acc1 = __builtin_elementwise_fma(w2[k + 1], f32x2{h1, h1}, acc1);
            acc2 = __builtin_elementwise_fma(w2[k + 2], f32x2{h2, h2}, acc2);
            acc3 = __builtin_elementwise_fma(w2[k + 3], f32x2{h3, h3}, acc3);
        }
        f32x2 a = (acc0 + acc1) + (acc2 + acc3);

        f32x2 mypair;
        if (wid == 0) mypair = f32x2{sigf(a.x), sigf(a.y)};        // {sig i, sig f}
        else          mypair = f32x2{tanhf_fast(a.x), sigf(a.y)};  // {tanh g, sig o}
        if (active) sEx[t & 1][wid][uu] = mypair;
        __syncthreads();
        f32x2 other = sEx[t & 1][wid ^ 1][uu];
        f32x2 ivfv = (wid == 0) ? mypair : other;   // {sig i, sig f}
        f32x2 gvov = (wid == 0) ? other : mypair;   // {tanh g, sig o}
        c = fmaf(ivfv.y, c, ivfv.x * gvov.x);
        hv = gvov.y * tanhf_fast(c);
        if (wid == 0 && active) hbuf[t * 36 + uu] = hv;   // LDS only (lgkm)
    }

    __syncthreads();
    {
        f32x4* dst = (f32x4*)(hseq2 + (size_t)b * 256 * 36);
        const f32x4* src = (const f32x4*)hbuf;
        for (int i = threadIdx.x; i < 2304; i += 128) dst[i] = src[i];
    }
    if (threadIdx.x == 0)
        __hip_atomic_fetch_add(flag, 1, __ATOMIC_RELAXED, __HIP_MEMORY_SCOPE_AGENT);
}

// ---------------------------------------------------------------------------
// Kernel 5: mixed[b][o][n]; consumes hseq2[b][t][36]; LDS padded to 37
// ---------------------------------------------------------------------------
__global__ __launch_bounds__(256) void k_mixed(
    const float* __restrict__ blk, const float* __restrict__ hseq2,
    const float* __restrict__ mixW, const float* __restrict__ mixb,
    float* __restrict__ mixed)
{
    int bq = blockIdx.x;
    int b = bq >> 2, oq = bq & 3;        // 9 o's per block
    int tid = threadIdx.x;
    __shared__ float sH[256 * 37];
    __shared__ float sW[9 * 36];
    __shared__ float sBase[9];
    for (int idx = tid; idx < 9216; idx += 256) {
        int t = idx / 36, u = idx - t * 36;
        sH[t * 37 + u] = hseq2[(size_t)b * 9216 + idx];
    }
    for (int idx = tid; idx < 9 * 36; idx += 256) {
        int o = idx / 36, u = idx - o * 36;
        sW[idx] = mixW[(oq * 9 + o) * 72 + 36 + u];
    }
    if (tid < 9) {
        int o = oq * 9 + tid;
        float acc = mixb[o];
        for (int c = 0; c < 36; ++c) acc = fmaf(mixW[o * 72 + c], blk[b * 36 + c], acc);
        sBase[tid] = acc;
    }
    __syncthreads();
    int n = tid;
    #pragma unroll
    for (int o = 0; o < 9; ++o) {
        float acc = sBase[o];
        #pragma unroll
        for (int u = 0; u < 36; ++u)
            acc = fmaf(sW[o * 36 + u], sH[n * 37 + u], acc);
        mixed[((size_t)b * 36 + oq * 9 + o) * 256 + n] = acc;
    }
}

// ---------------------------------------------------------------------------
// Kernel 6: sparse nonzero writes into the pre-zeroed output
// ---------------------------------------------------------------------------
__global__ __launch_bounds__(256) void k_sparse(
    const float* __restrict__ mixed, float* __restrict__ out)
{
    int bg = blockIdx.x;
    int g = bg & 1, b = bg >> 1;
    int n = threadIdx.x;
    const float* mb = mixed + (size_t)b * 36 * 256;
    float vSub = mb[(size_t)g * 256 + n];
    float vSup = mb[(size_t)(2 + g) * 256 + n];
    float ch[16];
    #pragma unroll
    for (int k = 0; k < 16; ++k) ch[k] = mb[(size_t)(4 + 16 * g + k) * 256 + n];
    float d[16];
    #pragma unroll
    for (int e = 0; e < 16; ++e) {
        int r = e >> 2, cc = e & 3;
        float acc = 0.f;
        #pragma unroll
        for (int k = 0; k < 16; ++k) {
            float kv = pauliv(k >> 2, r >> 1, cc >> 1) * pauliv(k & 3, r & 1, cc & 1);
            if (kv == 1.f) acc = acc + ch[k];
            else if (kv == -1.f) acc = acc - ch[k];
        }
        d[e] = acc;
    }

    float* base = out + (size_t)bg * 1024 * 1024;
    #pragma unroll
    for (int r = 0; r < 4; ++r)
        *(f32x4*)(base + (size_t)(4 * n + r) * 1024 + 4 * n) =
            f32x4{d[r * 4 + 0], d[r * 4 + 1], d[r * 4 + 2], d[r * 4 + 3]};
    if (n > 0) {
        #pragma unroll
        for (int r = 0; r < 4; ++r)
            base[(size_t)(4 * n + r) * 1024 + 4 * (n - 1) + r] = (r < 2) ? vSub : -vSub;
    }
    if (n < 255) {
        #pragma unroll
        for (int r = 0; r < 4; ++r)
            base[(size_t)(4 * n + r) * 1024 + 4 * (n + 1) + r] = (r < 2) ? vSup : -vSup;
    }
}

// ---------------------------------------------------------------------------
extern "C" void kernel_launch(void* const* d_in, const int* in_sizes, int n_in,
                              void* d_out, int out_size, void* d_ws, size_t ws_size,
                              hipStream_t stream) {
    const float* x      = (const float*)d_in[0];
    const float* fdWin  = (const float*)d_in[1];
    const float* fdbin  = (const float*)d_in[2];
    const float* fdWmid = (const float*)d_in[3];
    const float* fdbmid = (const float*)d_in[4];
    const float* fdWout = (const float*)d_in[5];
    const float* fdbout = (const float*)d_in[6];
    const float* fdg    = (const float*)d_in[7];
    const float* fdbt   = (const float*)d_in[8];
    const float* bdWin  = (const float*)d_in[9];
    const float* bdbin  = (const float*)d_in[10];
    const float* bdWmid = (const float*)d_in[11];
    const float* bdbmid = (const float*)d_in[12];
    const float* bdWout = (const float*)d_in[13];
    const float* bdbout = (const float*)d_in[14];
    const float* bdg    = (const float*)d_in[15];
    const float* bdbt   = (const float*)d_in[16];
    const float* scWin  = (const float*)d_in[17];
    const float* scbin  = (const float*)d_in[18];
    const float* scWmid = (const float*)d_in[19];
    const float* scbmid = (const float*)d_in[20];
    const float* scWout = (const float*)d_in[21];
    const float* scbout = (const float*)d_in[22];
    const float* scg    = (const float*)d_in[23];
    const float* scbt   = (const float*)d_in[24];
    const float* Wih    = (const float*)d_in[25];
    const float* Whh    = (const float*)d_in[26];
    const float* bih    = (const float*)d_in[27];
    const float* bhh    = (const float*)d_in[28];
    const float* mixW   = (const float*)d_in[29];
    const float* mixb   = (const float*)d_in[30];

    float* ws    = (float*)d_ws;
    float* freq  = ws;                 // 1152            [b][s]
    float* blk   = ws + 1152;          // 1152            [b][s]
    float* fseq2 = ws + 2304;          // 294912          [s][b][t]
    float* Xg    = ws + 297216;        // 1179648         [b][t][36][4]
    float* hseq2 = ws + 1476864;       // 294912          [b][t][36]
    float* mixed = ws + 1771776;       // 294912          [b][o][n]
    float* actW  = Xg;                 // aliases Xg (dead until k_xg)
    int*   flag  = (int*)(ws + 2066688);

    float* out = (float*)d_out;
    long total4 = (long)out_size / 4;  // 16,777,216 f32x4

    k_mlp2_zero<<<2048, 1024, 0, stream>>>(x,
        fdWin, fdbin, fdWmid, fdbmid, fdWout, fdbout, fdg, fdbt,
        bdWin, bdbin, bdWmid, bdbmid, bdWout, bdbout, bdg, bdbt,
        freq, blk, out, total4);
    k_sc1<<<36, 512, 0, stream>>>(freq, scWin, scbin, scWmid, scbmid, scg, scbt, actW);
    k_sc2<<<144, 512, 0, stream>>>(actW, scWout, scbout, fseq2);
    k_xg<<<256, 512, 0, stream>>>(fseq2, Wih, bih, bhh, Xg, flag);
    k_lstm_heat<<<255, 128, 0, stream>>>(Xg, blk, Whh, hseq2, flag);
    k_mixed<<<128, 256, 0, stream>>>(blk, hseq2, mixW, mixb, mixed);
    k_sparse<<<64, 256, 0, stream>>>(mixed, out);
}